// Round 1
// baseline (135.496 us; speedup 1.0000x reference)
//
#include <hip/hip_runtime.h>

#define DD 256
#define BB 64
#define SS 256                       // H*W
#define K2 2.8853900817779268f      // 2*log2(e)
#define LOG2E 1.4426950408889634f
#define PROW 260                     // padded LDS panel row (floats)

static __device__ __forceinline__ float fast_rcp(float x) {
  return __builtin_amdgcn_rcpf(x);
}

// ---- kernel 1: transpose wv_w into wvT (blocks 0..15) + att_r = pe@wo^T+b (blocks 16..16+T) ----
__global__ __launch_bounds__(256) void k_prep(
    const float* __restrict__ wv_w,
    const float* __restrict__ wo_w, const float* __restrict__ wo_b,
    float* __restrict__ wvT, float* __restrict__ att_r, int T)
{
  const int tid = threadIdx.x;
  if (blockIdx.x < 16) {
    const int bi = blockIdx.x >> 2;   // d-tile
    const int bj = blockIdx.x & 3;    // c-tile
    __shared__ float tile[64 * 65];
#pragma unroll
    for (int p = 0; p < 4; ++p) {
      int row = p * 16 + (tid >> 4);          // local d
      int col = (tid & 15) * 4;               // local c
      float4 v = *reinterpret_cast<const float4*>(wv_w + (size_t)(bi*64 + row)*DD + bj*64 + col);
      tile[row*65 + col + 0] = v.x;
      tile[row*65 + col + 1] = v.y;
      tile[row*65 + col + 2] = v.z;
      tile[row*65 + col + 3] = v.w;
    }
    __syncthreads();
#pragma unroll
    for (int p = 0; p < 4; ++p) {
      int orow = p * 16 + (tid >> 4);   // local c
      int ocol = (tid & 15) * 4;        // local d
      float4 o;
      o.x = tile[(ocol+0)*65 + orow];
      o.y = tile[(ocol+1)*65 + orow];
      o.z = tile[(ocol+2)*65 + orow];
      o.w = tile[(ocol+3)*65 + orow];
      *reinterpret_cast<float4*>(wvT + (size_t)(bj*64 + orow)*DD + bi*64 + ocol) = o;
    }
    return;
  }
  // ---- att_r branch ----
  const int t = blockIdx.x - 16;
  if (t >= T) return;
  __shared__ float pe[DD];
  {
    int i = tid >> 1;
    double r = pow(10000.0, -(double)(2*i) / 256.0);
    double ang = (double)t * r;
    pe[tid] = (float)((tid & 1) ? cos(ang) : sin(ang));
  }
  __syncthreads();
  const float4* wr = reinterpret_cast<const float4*>(wo_w + (size_t)tid * DD);
  const float4* pp = reinterpret_cast<const float4*>(pe);
  float acc = 0.f;
#pragma unroll 8
  for (int k = 0; k < 64; ++k) {
    float4 w4 = wr[k]; float4 p4 = pp[k];
    acc = fmaf(w4.x, p4.x, acc);
    acc = fmaf(w4.y, p4.y, acc);
    acc = fmaf(w4.z, p4.z, acc);
    acc = fmaf(w4.w, p4.w, acc);
  }
  att_r[(size_t)t*DD + tid] = acc + wo_b[tid];
}

// ---- kernel 2: att_x[b][s][d] = sum_c x[b][c][s] * wvT[c][d] + wv_b[d] ----
// grid (8 s-tiles of 32, 64 b), block 256.  Per-thread 4s x 8d register tile.
__global__ __launch_bounds__(256) void k_attx(
    const float* __restrict__ x, const float* __restrict__ wvT,
    const float* __restrict__ wv_b, float* __restrict__ att_x)
{
  const int b  = blockIdx.y;
  const int s0 = blockIdx.x * 32;
  const int tid = threadIdx.x;
  const int sg = tid >> 5;   // 0..7 -> 4 s each
  const int dg = tid & 31;   // 0..31 -> 8 d each
  const float* xb = x + (size_t)b * DD * SS;   // [c][s]
  __shared__ float wt[16 * 256];
  float acc[4][8];
#pragma unroll
  for (int j = 0; j < 4; ++j)
#pragma unroll
    for (int r = 0; r < 8; ++r) acc[j][r] = 0.f;

  for (int cc = 0; cc < DD; cc += 16) {
    __syncthreads();
#pragma unroll
    for (int k = 0; k < 4; ++k) {
      int flat = k * 256 + tid;            // 0..1023
      int row = flat >> 6;                 // 0..15
      int col = (flat & 63) * 4;
      *reinterpret_cast<float4*>(&wt[row*256 + col]) =
        *reinterpret_cast<const float4*>(wvT + (size_t)(cc + row)*DD + col);
    }
    __syncthreads();
#pragma unroll
    for (int ci = 0; ci < 16; ++ci) {
      const int c = cc + ci;
      float4 xv = *reinterpret_cast<const float4*>(xb + (size_t)c * SS + s0 + sg*4);
      float wv[8];
      *reinterpret_cast<float4*>(&wv[0]) = *reinterpret_cast<const float4*>(&wt[ci*256 + dg*8]);
      *reinterpret_cast<float4*>(&wv[4]) = *reinterpret_cast<const float4*>(&wt[ci*256 + dg*8 + 4]);
      const float xs_[4] = {xv.x, xv.y, xv.z, xv.w};
#pragma unroll
      for (int j = 0; j < 4; ++j)
#pragma unroll
        for (int r = 0; r < 8; ++r)
          acc[j][r] = fmaf(xs_[j], wv[r], acc[j][r]);
    }
  }
  float bias[8];
  *reinterpret_cast<float4*>(&bias[0]) = *reinterpret_cast<const float4*>(wv_b + dg*8);
  *reinterpret_cast<float4*>(&bias[4]) = *reinterpret_cast<const float4*>(wv_b + dg*8 + 4);
#pragma unroll
  for (int j = 0; j < 4; ++j) {
    float o[8];
#pragma unroll
    for (int r = 0; r < 8; ++r) o[r] = acc[j][r] + bias[r];
    float* dst = att_x + ((size_t)(b*SS + s0 + sg*4 + j))*DD + dg*8;
    *reinterpret_cast<float4*>(dst)     = *reinterpret_cast<float4*>(&o[0]);
    *reinterpret_cast<float4*>(dst + 4) = *reinterpret_cast<float4*>(&o[4]);
  }
}

// ---- kernel 3: scores + softmax -> alpha.  grid (4 t-quarters, 64 b), block 1024. ----
// Thread (c = tid>>8, s = tid&255) holds att_x[b][s][c*64 .. c*64+63]*K2 in registers.
__global__ __launch_bounds__(1024) void k_score(
    const float* __restrict__ att_x, const float* __restrict__ att_r,
    const float* __restrict__ we_w, float* __restrict__ alpha, int T)
{
  const int b = blockIdx.y;
  const int tq = blockIdx.x;
  const int tchunk = (T + 3) >> 2;
  const int t0 = tq * tchunk;
  const int nT = (T - t0 < tchunk) ? (T - t0) : tchunk;
  if (nT <= 0) return;

  const int tid = threadIdx.x;
  const int c = tid >> 8;        // 0..3
  const int s = tid & 255;
  const int lane = tid & 63;
  const int wid = tid >> 6;

  __shared__ float panel[64 * PROW];   // 66560 B staging panel
  __shared__ float attrK[8 * 256];     // K2-scaled att_r rows for this t-chunk
  __shared__ float we_s[256];
  __shared__ float spart[1024];
  __shared__ float wredA[16];
  __shared__ float wredB[16];

  const float* axb = att_x + (size_t)b * SS * DD;
  float frag[64];
  {
    const int row = tid >> 4;          // 0..63
    const int c16 = (tid & 15) * 4;    // 0..60
    for (int p = 0; p < 4; ++p) {
      __syncthreads();
      const float* src = axb + (size_t)(p*64 + row) * DD + c16;
      float4 v0 = *reinterpret_cast<const float4*>(src);
      float4 v1 = *reinterpret_cast<const float4*>(src + 64);
      float4 v2 = *reinterpret_cast<const float4*>(src + 128);
      float4 v3 = *reinterpret_cast<const float4*>(src + 192);
      *reinterpret_cast<float4*>(&panel[row*PROW + c16      ]) = v0;
      *reinterpret_cast<float4*>(&panel[row*PROW + c16 + 64 ]) = v1;
      *reinterpret_cast<float4*>(&panel[row*PROW + c16 + 128]) = v2;
      *reinterpret_cast<float4*>(&panel[row*PROW + c16 + 192]) = v3;
      __syncthreads();
      if ((s >> 6) == p) {               // wave-uniform condition
        const int r = s & 63;
#pragma unroll
        for (int jg = 0; jg < 16; ++jg) {
          float4 f = *reinterpret_cast<const float4*>(&panel[r*PROW + c*64 + jg*4]);
          frag[jg*4+0] = f.x * K2;
          frag[jg*4+1] = f.y * K2;
          frag[jg*4+2] = f.z * K2;
          frag[jg*4+3] = f.w * K2;
        }
      }
    }
  }
  for (int idx = tid; idx < nT*256; idx += 1024)
    attrK[idx] = att_r[(size_t)t0*DD + idx] * K2;
  if (tid < 256) we_s[tid] = we_w[tid];
  __syncthreads();

  for (int tl = 0; tl < nT; ++tl) {
    // score partial: sum_j we[j] * rcp(exp(2*(attx+attr)) + 1)  (we*tanh = we - 2*we*r)
    float part = 0.f;
    const int ab = tl*256 + c*64;
    const int wb = c*64;
#pragma unroll
    for (int jg = 0; jg < 16; ++jg) {
      float4 a4 = *reinterpret_cast<const float4*>(&attrK[ab + jg*4]);   // wave-uniform
      float4 w4 = *reinterpret_cast<const float4*>(&we_s[wb + jg*4]);    // wave-uniform
      { float e0 = exp2f(frag[jg*4+0] + a4.x); part = fmaf(w4.x, fast_rcp(e0 + 1.f), part); }
      { float e1 = exp2f(frag[jg*4+1] + a4.y); part = fmaf(w4.y, fast_rcp(e1 + 1.f), part); }
      { float e2 = exp2f(frag[jg*4+2] + a4.z); part = fmaf(w4.z, fast_rcp(e2 + 1.f), part); }
      { float e3 = exp2f(frag[jg*4+3] + a4.w); part = fmaf(w4.w, fast_rcp(e3 + 1.f), part); }
    }
    spart[tid] = part;
    __syncthreads();
    // softmax over s (threads 0..255); score = -2 * sum_c part  (+const dropped)
    float sc_v = 0.f;
    float m = -3.0e38f;
    if (tid < 256) {
      sc_v = -2.f * (spart[tid] + spart[256 + tid] + spart[512 + tid] + spart[768 + tid]);
      m = sc_v;
    }
#pragma unroll
    for (int o = 32; o > 0; o >>= 1) m = fmaxf(m, __shfl_xor(m, o));
    if (lane == 0) wredA[wid] = m;
    __syncthreads();
    m = fmaxf(fmaxf(wredA[0], wredA[1]), fmaxf(wredA[2], wredA[3]));
    float ev = 0.f;
    if (tid < 256) ev = exp2f((sc_v - m) * LOG2E);
    float ssum = ev;
#pragma unroll
    for (int o = 32; o > 0; o >>= 1) ssum += __shfl_xor(ssum, o);
    if (lane == 0) wredB[wid] = ssum;
    __syncthreads();
    float S = wredB[0] + wredB[1] + wredB[2] + wredB[3];
    if (tid < 256)
      alpha[((size_t)b*T + (t0 + tl))*DD + s] = ev * fast_rcp(S);
    __syncthreads();
  }
}

// ---- kernel 4: out[b][t][d] = (1/256) * sum_s alpha[b][t][s] * att_x[b][s][d] ----
// grid (4 t-quarters, 64 b), block 1024: thread (d = tid&255, s-chunk = tid>>8).
__global__ __launch_bounds__(1024) void k_out(
    const float* __restrict__ att_x, const float* __restrict__ alpha,
    float* __restrict__ out, int T)
{
  const int b = blockIdx.y;
  const int tg = blockIdx.x;
  const int tchunk = (T + 3) >> 2;
  const int t0 = tg * tchunk;
  const int nT = (T - t0 < tchunk) ? (T - t0) : tchunk;
  if (nT <= 0) return;
  const int tid = threadIdx.x;
  const int d   = tid & 255;
  const int scg = tid >> 8;   // 0..3

  __shared__ float al[7 * 256];
  __shared__ float red[4 * 7 * 256];

  for (int idx = tid; idx < 7*256; idx += 1024)
    al[idx] = (idx < nT*256) ? alpha[((size_t)b*T + t0)*DD + idx] : 0.f;
  __syncthreads();

  float v[64];
  const float* ax = att_x + ((size_t)(b*SS) + scg*64) * DD + d;
#pragma unroll
  for (int i = 0; i < 64; ++i) v[i] = ax[(size_t)i * DD];

#pragma unroll
  for (int tl = 0; tl < 7; ++tl) {
    float a = 0.f;
#pragma unroll
    for (int i4 = 0; i4 < 16; ++i4) {
      float4 a4 = *reinterpret_cast<const float4*>(&al[tl*256 + scg*64 + i4*4]);  // wave-uniform
      a = fmaf(a4.x, v[i4*4+0], a);
      a = fmaf(a4.y, v[i4*4+1], a);
      a = fmaf(a4.z, v[i4*4+2], a);
      a = fmaf(a4.w, v[i4*4+3], a);
    }
    red[scg*1792 + tl*256 + d] = a;
  }
  __syncthreads();
  for (int idx = tid; idx < nT*256; idx += 1024) {
    float sum = red[idx] + red[1792 + idx] + red[2*1792 + idx] + red[3*1792 + idx];
    out[((size_t)b*T + t0)*DD + idx] = sum * (1.0f/256.0f);
  }
}

extern "C" void kernel_launch(void* const* d_in, const int* in_sizes, int n_in,
                              void* d_out, int out_size, void* d_ws, size_t ws_size,
                              hipStream_t stream) {
  (void)in_sizes; (void)n_in; (void)ws_size;
  const float* x    = (const float*)d_in[0];
  // d_in[1] = seq_len (device int scalar) -- T derived from out_size instead
  const float* wo_w = (const float*)d_in[2];
  const float* wo_b = (const float*)d_in[3];
  const float* wv_w = (const float*)d_in[4];
  const float* wv_b = (const float*)d_in[5];
  const float* we_w = (const float*)d_in[6];
  float* out = (float*)d_out;
  const int T = out_size / (BB * DD);

  float* att_x = (float*)d_ws;                     // 64*256*256 = 4194304 floats (16 MB)
  float* wvT   = att_x + (size_t)BB * SS * DD;     // 65536 floats
  float* att_r = wvT + DD * DD;                    // up to 64*256 reserved
  float* alpha = att_r + 64 * DD;                  // B*T*256 floats

  k_prep <<<dim3(16 + T), 256, 0, stream>>>(wv_w, wo_w, wo_b, wvT, att_r, T);
  k_attx <<<dim3(8, BB), 256, 0, stream>>>(x, wvT, wv_b, att_x);
  k_score<<<dim3(4, BB), 1024, 0, stream>>>(att_x, att_r, we_w, alpha, T);
  k_out  <<<dim3(4, BB), 1024, 0, stream>>>(att_x, alpha, out, T);
}

// Round 4
// 135.326 us; speedup vs baseline: 1.0013x; 1.0013x over previous
//
#include <hip/hip_runtime.h>

#define DD 256
#define BB 64
#define SS 256                       // H*W
#define K2 2.8853900817779268f      // 2*log2(e)
#define LOG2E 1.4426950408889634f

static __device__ __forceinline__ float fast_rcp(float x) {
  return __builtin_amdgcn_rcpf(x);
}

// ---- kernel 1: transpose wv_w into wvT (blocks 0..15) + att_r = pe@wo^T+b (blocks 16..16+T) ----
__global__ __launch_bounds__(256) void k_prep(
    const float* __restrict__ wv_w,
    const float* __restrict__ wo_w, const float* __restrict__ wo_b,
    float* __restrict__ wvT, float* __restrict__ att_r, int T)
{
  const int tid = threadIdx.x;
  if (blockIdx.x < 16) {
    const int bi = blockIdx.x >> 2;   // d-tile
    const int bj = blockIdx.x & 3;    // c-tile
    __shared__ float tile[64 * 65];
#pragma unroll
    for (int p = 0; p < 4; ++p) {
      int row = p * 16 + (tid >> 4);          // local d
      int col = (tid & 15) * 4;               // local c
      float4 v = *reinterpret_cast<const float4*>(wv_w + (size_t)(bi*64 + row)*DD + bj*64 + col);
      tile[row*65 + col + 0] = v.x;
      tile[row*65 + col + 1] = v.y;
      tile[row*65 + col + 2] = v.z;
      tile[row*65 + col + 3] = v.w;
    }
    __syncthreads();
#pragma unroll
    for (int p = 0; p < 4; ++p) {
      int orow = p * 16 + (tid >> 4);   // local c
      int ocol = (tid & 15) * 4;        // local d
      float4 o;
      o.x = tile[(ocol+0)*65 + orow];
      o.y = tile[(ocol+1)*65 + orow];
      o.z = tile[(ocol+2)*65 + orow];
      o.w = tile[(ocol+3)*65 + orow];
      *reinterpret_cast<float4*>(wvT + (size_t)(bj*64 + orow)*DD + bi*64 + ocol) = o;
    }
    return;
  }
  // ---- att_r branch ----
  const int t = blockIdx.x - 16;
  if (t >= T) return;
  __shared__ float pe[DD];
  {
    int i = tid >> 1;
    double r = pow(10000.0, -(double)(2*i) / 256.0);
    double ang = (double)t * r;
    pe[tid] = (float)((tid & 1) ? cos(ang) : sin(ang));
  }
  __syncthreads();
  const float4* wr = reinterpret_cast<const float4*>(wo_w + (size_t)tid * DD);
  const float4* pp = reinterpret_cast<const float4*>(pe);
  float acc = 0.f;
#pragma unroll 8
  for (int k = 0; k < 64; ++k) {
    float4 w4 = wr[k]; float4 p4 = pp[k];
    acc = fmaf(w4.x, p4.x, acc);
    acc = fmaf(w4.y, p4.y, acc);
    acc = fmaf(w4.z, p4.z, acc);
    acc = fmaf(w4.w, p4.w, acc);
  }
  att_r[(size_t)t*DD + tid] = acc + wo_b[tid];
}

// ---- kernel 2: att_x[b][s][d] = sum_c x[b][c][s] * wvT[c][d] + wv_b[d] ----
// grid (8 s-tiles of 32, 64 b), block 256.
// thread: sg = tid>>5 (4 s each), dg = tid&31 owns d = dg*4..+3 and 128+dg*4..+3
// 2-phase pipeline: global->reg prefetch overlapped with LDS compute (T14).
__global__ __launch_bounds__(256) void k_attx(
    const float* __restrict__ x, const float* __restrict__ wvT,
    const float* __restrict__ wv_b, float* __restrict__ att_x)
{
  const int b  = blockIdx.y;
  const int s0 = blockIdx.x * 32;
  const int tid = threadIdx.x;
  const int sg = tid >> 5;
  const int dg = tid & 31;
  const float* xb = x + (size_t)b * DD * SS;   // [c][s]

  __shared__ float wt[16 * 256];   // w chunk: rows c, cols d   (16 KB)
  __shared__ float xs[16 * 32];    // x chunk: rows c, cols s   (2 KB)

  float acc[4][8];
#pragma unroll
  for (int j = 0; j < 4; ++j)
#pragma unroll
    for (int r = 0; r < 8; ++r) acc[j][r] = 0.f;

  // staging sources (thread-linear, coalesced)
  const float* wsrc = wvT + (size_t)tid * 4;                               // + cc*16*DD + k*1024
  const float* xsrc = xb + (size_t)(tid >> 3) * SS + s0 + (tid & 7) * 4;   // rows 0..15 via tid<128

  float4 wA[4];
  float4 xA = make_float4(0.f, 0.f, 0.f, 0.f);
#pragma unroll
  for (int k = 0; k < 4; ++k)
    wA[k] = *reinterpret_cast<const float4*>(wsrc + k * 1024);
  if (tid < 128) xA = *reinterpret_cast<const float4*>(xsrc);

  for (int cc = 0; cc < 16; ++cc) {
    __syncthreads();                                  // LDS free
#pragma unroll
    for (int k = 0; k < 4; ++k)
      *reinterpret_cast<float4*>(&wt[tid * 4 + k * 1024]) = wA[k];
    if (tid < 128) *reinterpret_cast<float4*>(&xs[tid * 4]) = xA;
    if (cc < 15) {                                    // prefetch next chunk -> regs
#pragma unroll
      for (int k = 0; k < 4; ++k)
        wA[k] = *reinterpret_cast<const float4*>(wsrc + (size_t)(cc + 1) * 16 * DD + k * 1024);
      if (tid < 128) xA = *reinterpret_cast<const float4*>(xsrc + (size_t)(cc + 1) * 16 * SS);
    }
    __syncthreads();                                  // LDS ready
#pragma unroll
    for (int ci = 0; ci < 16; ++ci) {
      float4 xv = *reinterpret_cast<const float4*>(&xs[ci * 32 + sg * 4]);       // broadcast
      float4 w0 = *reinterpret_cast<const float4*>(&wt[ci * 256 + dg * 4]);
      float4 w1 = *reinterpret_cast<const float4*>(&wt[ci * 256 + 128 + dg * 4]);
      const float xarr[4] = {xv.x, xv.y, xv.z, xv.w};
#pragma unroll
      for (int j = 0; j < 4; ++j) {
        acc[j][0] = fmaf(xarr[j], w0.x, acc[j][0]);
        acc[j][1] = fmaf(xarr[j], w0.y, acc[j][1]);
        acc[j][2] = fmaf(xarr[j], w0.z, acc[j][2]);
        acc[j][3] = fmaf(xarr[j], w0.w, acc[j][3]);
        acc[j][4] = fmaf(xarr[j], w1.x, acc[j][4]);
        acc[j][5] = fmaf(xarr[j], w1.y, acc[j][5]);
        acc[j][6] = fmaf(xarr[j], w1.z, acc[j][6]);
        acc[j][7] = fmaf(xarr[j], w1.w, acc[j][7]);
      }
    }
  }

  float4 b0 = *reinterpret_cast<const float4*>(wv_b + dg * 4);
  float4 b1 = *reinterpret_cast<const float4*>(wv_b + 128 + dg * 4);
#pragma unroll
  for (int j = 0; j < 4; ++j) {
    float4 o0, o1;
    o0.x = acc[j][0] + b0.x; o0.y = acc[j][1] + b0.y;
    o0.z = acc[j][2] + b0.z; o0.w = acc[j][3] + b0.w;
    o1.x = acc[j][4] + b1.x; o1.y = acc[j][5] + b1.y;
    o1.z = acc[j][6] + b1.z; o1.w = acc[j][7] + b1.w;
    float* dst = att_x + ((size_t)(b * SS + s0 + sg * 4 + j)) * DD + dg * 4;
    *reinterpret_cast<float4*>(dst)       = o0;
    *reinterpret_cast<float4*>(dst + 128) = o1;
  }
}

// ---- kernel 3: scores + softmax -> alpha.  grid (ceil(T/4), 64 b), block 1024. ----
// thread: s = tid>>2 (256 s), c = tid&3 owns contiguous d in [c*64, c*64+64).
// frag loaded straight from global (att_x is L2/L3-resident); c-reduce = 2 shuffles.
__global__ __launch_bounds__(1024) void k_score(
    const float* __restrict__ att_x, const float* __restrict__ att_r,
    const float* __restrict__ we_w, float* __restrict__ alpha, int T)
{
  const int b  = blockIdx.y;
  const int t0 = blockIdx.x * 4;
  int nT = T - t0; if (nT > 4) nT = 4;
  if (nT <= 0) return;
  const int tid  = threadIdx.x;
  const int s    = tid >> 2;
  const int c    = tid & 3;
  const int wv   = tid >> 6;     // 0..15
  const int lane = tid & 63;

  __shared__ float attrS[4][4 * 68];   // [tl][c*68 + jj]: quarter-major, +4 pad
  __shared__ float weS[4 * 68];
  __shared__ float wredA[4][16];
  __shared__ float wredB[4][16];

  if (tid < 256)
    weS[(tid >> 6) * 68 + (tid & 63)] = we_w[tid];
  for (int idx = tid; idx < nT * 256; idx += 1024) {
    int tl = idx >> 8, d = idx & 255;
    attrS[tl][(d >> 6) * 68 + (d & 63)] = att_r[(size_t)(t0 + tl) * DD + d] * K2;
  }

  // frag[jj] = K2 * att_x[b][s][c*64 + jj]  (float4-coalesced: lane l -> 16B at l*256B)
  float frag[64];
  {
    const float4* ax4 = reinterpret_cast<const float4*>(att_x + ((size_t)(b * SS + s)) * DD + c * 64);
#pragma unroll
    for (int jg = 0; jg < 16; ++jg) {
      float4 f = ax4[jg];
      frag[jg*4+0] = f.x * K2;
      frag[jg*4+1] = f.y * K2;
      frag[jg*4+2] = f.z * K2;
      frag[jg*4+3] = f.w * K2;
    }
  }
  __syncthreads();

  for (int tl = 0; tl < nT; ++tl) {
    float part = 0.f;
    const float* aS = &attrS[tl][c * 68];
    const float* wS = &weS[c * 68];
#pragma unroll
    for (int jg = 0; jg < 16; ++jg) {
      float4 a4 = *reinterpret_cast<const float4*>(aS + jg * 4);
      float4 w4 = *reinterpret_cast<const float4*>(wS + jg * 4);
      part = fmaf(w4.x, fast_rcp(exp2f(frag[jg*4+0] + a4.x) + 1.f), part);
      part = fmaf(w4.y, fast_rcp(exp2f(frag[jg*4+1] + a4.y) + 1.f), part);
      part = fmaf(w4.z, fast_rcp(exp2f(frag[jg*4+2] + a4.z) + 1.f), part);
      part = fmaf(w4.w, fast_rcp(exp2f(frag[jg*4+3] + a4.w) + 1.f), part);
    }
    // reduce over c (lane bits 0..1)
    part += __shfl_xor(part, 1);
    part += __shfl_xor(part, 2);
    float sc = -2.f * part;          // + softmax-invariant const (dropped)
    // wave max over its 16 s (lane bits 2..5)
    float m = sc;
    m = fmaxf(m, __shfl_xor(m, 4));
    m = fmaxf(m, __shfl_xor(m, 8));
    m = fmaxf(m, __shfl_xor(m, 16));
    m = fmaxf(m, __shfl_xor(m, 32));
    if (lane == 0) wredA[tl][wv] = m;
    __syncthreads();
#pragma unroll
    for (int k = 0; k < 16; ++k) m = fmaxf(m, wredA[tl][k]);
    float ev = exp2f((sc - m) * LOG2E);
    float ss = ev;
    ss += __shfl_xor(ss, 4);
    ss += __shfl_xor(ss, 8);
    ss += __shfl_xor(ss, 16);
    ss += __shfl_xor(ss, 32);
    if (lane == 0) wredB[tl][wv] = ss;   // = sum over this wave's 16 distinct s (c-copies NOT mixed)
    __syncthreads();
    float S4 = 0.f;
#pragma unroll
    for (int k = 0; k < 16; ++k) S4 += wredB[tl][k];   // = full sum over 256 s
    if (c == 0)
      alpha[((size_t)b * T + (t0 + tl)) * DD + s] = ev * fast_rcp(S4);
  }
}

// ---- kernel 4: out[b][t][d] = (1/256) * sum_s alpha[b][t][s] * att_x[b][s][d] ----
__global__ __launch_bounds__(1024) void k_out(
    const float* __restrict__ att_x, const float* __restrict__ alpha,
    float* __restrict__ out, int T)
{
  const int b = blockIdx.y;
  const int tg = blockIdx.x;
  const int tchunk = (T + 3) >> 2;
  const int t0 = tg * tchunk;
  const int nT = (T - t0 < tchunk) ? (T - t0) : tchunk;
  if (nT <= 0) return;
  const int tid = threadIdx.x;
  const int d   = tid & 255;
  const int scg = tid >> 8;   // 0..3

  __shared__ float al[7 * 256];
  __shared__ float red[4 * 7 * 256];

  for (int idx = tid; idx < 7*256; idx += 1024)
    al[idx] = (idx < nT*256) ? alpha[((size_t)b*T + t0)*DD + idx] : 0.f;
  __syncthreads();

  float v[64];
  const float* ax = att_x + ((size_t)(b*SS) + scg*64) * DD + d;
#pragma unroll
  for (int i = 0; i < 64; ++i) v[i] = ax[(size_t)i * DD];

#pragma unroll
  for (int tl = 0; tl < 7; ++tl) {
    float a = 0.f;
#pragma unroll
    for (int i4 = 0; i4 < 16; ++i4) {
      float4 a4 = *reinterpret_cast<const float4*>(&al[tl*256 + scg*64 + i4*4]);  // wave-uniform
      a = fmaf(a4.x, v[i4*4+0], a);
      a = fmaf(a4.y, v[i4*4+1], a);
      a = fmaf(a4.z, v[i4*4+2], a);
      a = fmaf(a4.w, v[i4*4+3], a);
    }
    red[scg*1792 + tl*256 + d] = a;
  }
  __syncthreads();
  for (int idx = tid; idx < nT*256; idx += 1024) {
    float sum = red[idx] + red[1792 + idx] + red[2*1792 + idx] + red[3*1792 + idx];
    out[((size_t)b*T + t0)*DD + idx] = sum * (1.0f/256.0f);
  }
}

extern "C" void kernel_launch(void* const* d_in, const int* in_sizes, int n_in,
                              void* d_out, int out_size, void* d_ws, size_t ws_size,
                              hipStream_t stream) {
  (void)in_sizes; (void)n_in; (void)ws_size;
  const float* x    = (const float*)d_in[0];
  // d_in[1] = seq_len (device int scalar) -- T derived from out_size instead
  const float* wo_w = (const float*)d_in[2];
  const float* wo_b = (const float*)d_in[3];
  const float* wv_w = (const float*)d_in[4];
  const float* wv_b = (const float*)d_in[5];
  const float* we_w = (const float*)d_in[6];
  float* out = (float*)d_out;
  const int T = out_size / (BB * DD);

  float* att_x = (float*)d_ws;                     // 64*256*256 floats (16 MB)
  float* wvT   = att_x + (size_t)BB * SS * DD;     // 65536 floats
  float* att_r = wvT + DD * DD;                    // 64*DD reserved
  float* alpha = att_r + 64 * DD;                  // B*T*256 floats

  k_prep <<<dim3(16 + T), 256, 0, stream>>>(wv_w, wo_w, wo_b, wvT, att_r, T);
  k_attx <<<dim3(8, BB), 256, 0, stream>>>(x, wvT, wv_b, att_x);
  k_score<<<dim3((T + 3) / 4, BB), 1024, 0, stream>>>(att_x, att_r, we_w, alpha, T);
  k_out  <<<dim3(4, BB), 1024, 0, stream>>>(att_x, alpha, out, T);
}

// Round 5
// 101.342 us; speedup vs baseline: 1.3370x; 1.3353x over previous
//
#include <hip/hip_runtime.h>

#define DD 256
#define BB 64
#define SS 256                       // H*W
#define K2 2.8853900817779268f      // 2*log2(e)
#define LOG2E 1.4426950408889634f
#define MAXT 32

#if __has_builtin(__builtin_amdgcn_exp2f)
#define EXP2(x) __builtin_amdgcn_exp2f(x)
#else
#define EXP2(x) exp2f(x)
#endif

static __device__ __forceinline__ float fast_rcp(float x) {
  return __builtin_amdgcn_rcpf(x);
}

// ---- kernel 1: transpose wv_w into wvT (blocks 0..15) + att_r = pe@wo^T+b (blocks 16..16+T) ----
__global__ __launch_bounds__(256) void k_prep(
    const float* __restrict__ wv_w,
    const float* __restrict__ wo_w, const float* __restrict__ wo_b,
    float* __restrict__ wvT, float* __restrict__ att_r, int T)
{
  const int tid = threadIdx.x;
  if (blockIdx.x < 16) {
    const int bi = blockIdx.x >> 2;   // d-tile
    const int bj = blockIdx.x & 3;    // c-tile
    __shared__ float tile[64 * 65];
#pragma unroll
    for (int p = 0; p < 4; ++p) {
      int row = p * 16 + (tid >> 4);          // local d
      int col = (tid & 15) * 4;               // local c
      float4 v = *reinterpret_cast<const float4*>(wv_w + (size_t)(bi*64 + row)*DD + bj*64 + col);
      tile[row*65 + col + 0] = v.x;
      tile[row*65 + col + 1] = v.y;
      tile[row*65 + col + 2] = v.z;
      tile[row*65 + col + 3] = v.w;
    }
    __syncthreads();
#pragma unroll
    for (int p = 0; p < 4; ++p) {
      int orow = p * 16 + (tid >> 4);   // local c
      int ocol = (tid & 15) * 4;        // local d
      float4 o;
      o.x = tile[(ocol+0)*65 + orow];
      o.y = tile[(ocol+1)*65 + orow];
      o.z = tile[(ocol+2)*65 + orow];
      o.w = tile[(ocol+3)*65 + orow];
      *reinterpret_cast<float4*>(wvT + (size_t)(bj*64 + orow)*DD + bi*64 + ocol) = o;
    }
    return;
  }
  // ---- att_r branch ----
  const int t = blockIdx.x - 16;
  if (t >= T) return;
  __shared__ float pe[DD];
  {
    int i = tid >> 1;
    double r = pow(10000.0, -(double)(2*i) / 256.0);
    double ang = (double)t * r;
    pe[tid] = (float)((tid & 1) ? cos(ang) : sin(ang));
  }
  __syncthreads();
  const float4* wr = reinterpret_cast<const float4*>(wo_w + (size_t)tid * DD);
  const float4* pp = reinterpret_cast<const float4*>(pe);
  float acc = 0.f;
#pragma unroll 8
  for (int k = 0; k < 64; ++k) {
    float4 w4 = wr[k]; float4 p4 = pp[k];
    acc = fmaf(w4.x, p4.x, acc);
    acc = fmaf(w4.y, p4.y, acc);
    acc = fmaf(w4.z, p4.z, acc);
    acc = fmaf(w4.w, p4.w, acc);
  }
  att_r[(size_t)t*DD + tid] = acc + wo_b[tid];
}

// ---- kernel 2: att_x[b][s][d] = sum_c x[b][c][s] * wvT[c][d] + wv_b[d] ----
// grid (8 s-tiles of 32, 64 b), block 256. 2-phase reg-prefetch pipeline.
__global__ __launch_bounds__(256) void k_attx(
    const float* __restrict__ x, const float* __restrict__ wvT,
    const float* __restrict__ wv_b, float* __restrict__ att_x)
{
  const int b  = blockIdx.y;
  const int s0 = blockIdx.x * 32;
  const int tid = threadIdx.x;
  const int sg = tid >> 5;
  const int dg = tid & 31;
  const float* xb = x + (size_t)b * DD * SS;   // [c][s]

  __shared__ float wt[16 * 256];   // w chunk: rows c, cols d   (16 KB)
  __shared__ float xs[16 * 32];    // x chunk: rows c, cols s   (2 KB)

  float acc[4][8];
#pragma unroll
  for (int j = 0; j < 4; ++j)
#pragma unroll
    for (int r = 0; r < 8; ++r) acc[j][r] = 0.f;

  const float* wsrc = wvT + (size_t)tid * 4;                               // + cc*16*DD + k*1024
  const float* xsrc = xb + (size_t)(tid >> 3) * SS + s0 + (tid & 7) * 4;   // rows 0..15 via tid<128

  float4 wA[4];
  float4 xA = make_float4(0.f, 0.f, 0.f, 0.f);
#pragma unroll
  for (int k = 0; k < 4; ++k)
    wA[k] = *reinterpret_cast<const float4*>(wsrc + k * 1024);
  if (tid < 128) xA = *reinterpret_cast<const float4*>(xsrc);

  for (int cc = 0; cc < 16; ++cc) {
    __syncthreads();                                  // LDS free
#pragma unroll
    for (int k = 0; k < 4; ++k)
      *reinterpret_cast<float4*>(&wt[tid * 4 + k * 1024]) = wA[k];
    if (tid < 128) *reinterpret_cast<float4*>(&xs[tid * 4]) = xA;
    if (cc < 15) {                                    // prefetch next chunk -> regs
#pragma unroll
      for (int k = 0; k < 4; ++k)
        wA[k] = *reinterpret_cast<const float4*>(wsrc + (size_t)(cc + 1) * 16 * DD + k * 1024);
      if (tid < 128) xA = *reinterpret_cast<const float4*>(xsrc + (size_t)(cc + 1) * 16 * SS);
    }
    __syncthreads();                                  // LDS ready
#pragma unroll
    for (int ci = 0; ci < 16; ++ci) {
      float4 xv = *reinterpret_cast<const float4*>(&xs[ci * 32 + sg * 4]);       // broadcast
      float4 w0 = *reinterpret_cast<const float4*>(&wt[ci * 256 + dg * 4]);
      float4 w1 = *reinterpret_cast<const float4*>(&wt[ci * 256 + 128 + dg * 4]);
      const float xarr[4] = {xv.x, xv.y, xv.z, xv.w};
#pragma unroll
      for (int j = 0; j < 4; ++j) {
        acc[j][0] = fmaf(xarr[j], w0.x, acc[j][0]);
        acc[j][1] = fmaf(xarr[j], w0.y, acc[j][1]);
        acc[j][2] = fmaf(xarr[j], w0.z, acc[j][2]);
        acc[j][3] = fmaf(xarr[j], w0.w, acc[j][3]);
        acc[j][4] = fmaf(xarr[j], w1.x, acc[j][4]);
        acc[j][5] = fmaf(xarr[j], w1.y, acc[j][5]);
        acc[j][6] = fmaf(xarr[j], w1.z, acc[j][6]);
        acc[j][7] = fmaf(xarr[j], w1.w, acc[j][7]);
      }
    }
  }

  float4 b0 = *reinterpret_cast<const float4*>(wv_b + dg * 4);
  float4 b1 = *reinterpret_cast<const float4*>(wv_b + 128 + dg * 4);
#pragma unroll
  for (int j = 0; j < 4; ++j) {
    float4 o0, o1;
    o0.x = acc[j][0] + b0.x; o0.y = acc[j][1] + b0.y;
    o0.z = acc[j][2] + b0.z; o0.w = acc[j][3] + b0.w;
    o1.x = acc[j][4] + b1.x; o1.y = acc[j][5] + b1.y;
    o1.z = acc[j][6] + b1.z; o1.w = acc[j][7] + b1.w;
    float* dst = att_x + ((size_t)(b * SS + s0 + sg * 4 + j)) * DD + dg * 4;
    *reinterpret_cast<float4*>(dst)       = o0;
    *reinterpret_cast<float4*>(dst + 128) = o1;
  }
}

// ---- kernel 3: raw scores (no softmax).  grid (4 s-tiles of 64, 64 b), block 1024. ----
// thread: s = tid>>4 (64 s/block), c = tid&15 owns d in [c*16, c*16+16).
// frag = 16 regs -> att_x read ONCE; T-loop (all 26 t) inside, no barriers in loop.
__global__ __launch_bounds__(1024) void k_score2(
    const float* __restrict__ att_x, const float* __restrict__ att_r,
    const float* __restrict__ we_w, float* __restrict__ score, int T)
{
  const int b  = blockIdx.y;
  const int s0 = blockIdx.x * 64;
  const int tid = threadIdx.x;
  const int s  = tid >> 4;       // 0..63
  const int c  = tid & 15;       // 0..15

  __shared__ float attrS[MAXT * 320];   // [t][c*20 + j], c-stride 20: 2-way bank alias (free)
  __shared__ float scS[MAXT * 64];

  // frag[j] = K2 * att_x[b][s0+s][c*16 + j]
  float f0x, f0y, f0z, f0w, f1x, f1y, f1z, f1w;
  float f2x, f2y, f2z, f2w, f3x, f3y, f3z, f3w;
  {
    const float4* ax4 = reinterpret_cast<const float4*>(
        att_x + ((size_t)(b * SS + s0 + s)) * DD + c * 16);
    float4 a = ax4[0], bq = ax4[1], cq = ax4[2], dq = ax4[3];
    f0x = a.x*K2;  f0y = a.y*K2;  f0z = a.z*K2;  f0w = a.w*K2;
    f1x = bq.x*K2; f1y = bq.y*K2; f1z = bq.z*K2; f1w = bq.w*K2;
    f2x = cq.x*K2; f2y = cq.y*K2; f2z = cq.z*K2; f2w = cq.w*K2;
    f3x = dq.x*K2; f3y = dq.y*K2; f3z = dq.z*K2; f3w = dq.w*K2;
  }
  // we (tl-invariant) -> regs
  float4 w0, w1, w2, w3;
  {
    const float4* we4 = reinterpret_cast<const float4*>(we_w + c * 16);
    w0 = we4[0]; w1 = we4[1]; w2 = we4[2]; w3 = we4[3];
  }
  // stage att_r * K2 into LDS (padded layout)
  for (int idx = tid; idx < T * 256; idx += 1024) {
    int t = idx >> 8, d = idx & 255;
    attrS[t * 320 + (d >> 4) * 20 + (d & 15)] = att_r[(size_t)t * DD + d] * K2;
  }
  __syncthreads();

  for (int tl = 0; tl < T; ++tl) {
    const float* aS = &attrS[tl * 320 + c * 20];
    float4 a0 = *reinterpret_cast<const float4*>(aS);
    float4 a1 = *reinterpret_cast<const float4*>(aS + 4);
    float4 a2 = *reinterpret_cast<const float4*>(aS + 8);
    float4 a3 = *reinterpret_cast<const float4*>(aS + 12);
    float part = 0.f;
    part = fmaf(w0.x, fast_rcp(EXP2(f0x + a0.x) + 1.f), part);
    part = fmaf(w0.y, fast_rcp(EXP2(f0y + a0.y) + 1.f), part);
    part = fmaf(w0.z, fast_rcp(EXP2(f0z + a0.z) + 1.f), part);
    part = fmaf(w0.w, fast_rcp(EXP2(f0w + a0.w) + 1.f), part);
    part = fmaf(w1.x, fast_rcp(EXP2(f1x + a1.x) + 1.f), part);
    part = fmaf(w1.y, fast_rcp(EXP2(f1y + a1.y) + 1.f), part);
    part = fmaf(w1.z, fast_rcp(EXP2(f1z + a1.z) + 1.f), part);
    part = fmaf(w1.w, fast_rcp(EXP2(f1w + a1.w) + 1.f), part);
    part = fmaf(w2.x, fast_rcp(EXP2(f2x + a2.x) + 1.f), part);
    part = fmaf(w2.y, fast_rcp(EXP2(f2y + a2.y) + 1.f), part);
    part = fmaf(w2.z, fast_rcp(EXP2(f2z + a2.z) + 1.f), part);
    part = fmaf(w2.w, fast_rcp(EXP2(f2w + a2.w) + 1.f), part);
    part = fmaf(w3.x, fast_rcp(EXP2(f3x + a3.x) + 1.f), part);
    part = fmaf(w3.y, fast_rcp(EXP2(f3y + a3.y) + 1.f), part);
    part = fmaf(w3.z, fast_rcp(EXP2(f3z + a3.z) + 1.f), part);
    part = fmaf(w3.w, fast_rcp(EXP2(f3w + a3.w) + 1.f), part);
    // reduce over c (lane bits 0..3)
    part += __shfl_xor(part, 1);
    part += __shfl_xor(part, 2);
    part += __shfl_xor(part, 4);
    part += __shfl_xor(part, 8);
    if (c == 0) scS[tl * 64 + s] = -2.f * part;   // + softmax-invariant const (dropped)
  }
  __syncthreads();
  // coalesced score write: score[b][t][s0+sl]
  for (int idx = tid; idx < T * 64; idx += 1024) {
    int t = idx >> 6, sl = idx & 63;
    score[((size_t)b * T + t) * SS + s0 + sl] = scS[idx];
  }
}

// ---- kernel 3b: softmax in-place over score rows.  grid (T, 64 b), block 64 (1 wave). ----
__global__ __launch_bounds__(64) void k_softmax(float* __restrict__ score, int T)
{
  const int t = blockIdx.x;
  const int b = blockIdx.y;
  const int lane = threadIdx.x;
  float4* row = reinterpret_cast<float4*>(score + ((size_t)b * T + t) * SS);
  float4 v = row[lane];
  float m = fmaxf(fmaxf(v.x, v.y), fmaxf(v.z, v.w));
  m = fmaxf(m, __shfl_xor(m, 1));
  m = fmaxf(m, __shfl_xor(m, 2));
  m = fmaxf(m, __shfl_xor(m, 4));
  m = fmaxf(m, __shfl_xor(m, 8));
  m = fmaxf(m, __shfl_xor(m, 16));
  m = fmaxf(m, __shfl_xor(m, 32));
  float4 ev;
  ev.x = EXP2((v.x - m) * LOG2E);
  ev.y = EXP2((v.y - m) * LOG2E);
  ev.z = EXP2((v.z - m) * LOG2E);
  ev.w = EXP2((v.w - m) * LOG2E);
  float ss = ev.x + ev.y + ev.z + ev.w;
  ss += __shfl_xor(ss, 1);
  ss += __shfl_xor(ss, 2);
  ss += __shfl_xor(ss, 4);
  ss += __shfl_xor(ss, 8);
  ss += __shfl_xor(ss, 16);
  ss += __shfl_xor(ss, 32);
  float r = fast_rcp(ss);
  ev.x *= r; ev.y *= r; ev.z *= r; ev.w *= r;
  row[lane] = ev;
}

// ---- kernel 4: out[b][t][d] = (1/256) * sum_s alpha[b][t][s] * att_x[b][s][d] ----
// grid (64 b, 4 tg): same-b blocks land on the SAME XCD (stride 64 % 8 == 0).
__global__ __launch_bounds__(1024) void k_out(
    const float* __restrict__ att_x, const float* __restrict__ alpha,
    float* __restrict__ out, int T)
{
  const int b  = blockIdx.x;
  const int tg = blockIdx.y;
  const int tchunk = (T + 3) >> 2;
  const int t0 = tg * tchunk;
  const int nT = (T - t0 < tchunk) ? (T - t0) : tchunk;
  if (nT <= 0) return;
  const int tid = threadIdx.x;
  const int d   = tid & 255;
  const int scg = tid >> 8;   // 0..3

  __shared__ float al[7 * 256];
  __shared__ float red[4 * 7 * 256];

  for (int idx = tid; idx < 7*256; idx += 1024)
    al[idx] = (idx < nT*256) ? alpha[((size_t)b*T + t0)*SS + idx] : 0.f;
  __syncthreads();

  float v[64];
  const float* ax = att_x + ((size_t)(b*SS) + scg*64) * DD + d;
#pragma unroll
  for (int i = 0; i < 64; ++i) v[i] = ax[(size_t)i * DD];

#pragma unroll
  for (int tl = 0; tl < 7; ++tl) {
    float a = 0.f;
#pragma unroll
    for (int i4 = 0; i4 < 16; ++i4) {
      float4 a4 = *reinterpret_cast<const float4*>(&al[tl*256 + scg*64 + i4*4]);  // wave-uniform
      a = fmaf(a4.x, v[i4*4+0], a);
      a = fmaf(a4.y, v[i4*4+1], a);
      a = fmaf(a4.z, v[i4*4+2], a);
      a = fmaf(a4.w, v[i4*4+3], a);
    }
    red[scg*1792 + tl*256 + d] = a;
  }
  __syncthreads();
  for (int idx = tid; idx < nT*256; idx += 1024) {
    float sum = red[idx] + red[1792 + idx] + red[2*1792 + idx] + red[3*1792 + idx];
    out[((size_t)b*T + t0)*SS + idx] = sum * (1.0f/256.0f);
  }
}

extern "C" void kernel_launch(void* const* d_in, const int* in_sizes, int n_in,
                              void* d_out, int out_size, void* d_ws, size_t ws_size,
                              hipStream_t stream) {
  (void)in_sizes; (void)n_in; (void)ws_size;
  const float* x    = (const float*)d_in[0];
  // d_in[1] = seq_len (device int scalar) -- T derived from out_size instead
  const float* wo_w = (const float*)d_in[2];
  const float* wo_b = (const float*)d_in[3];
  const float* wv_w = (const float*)d_in[4];
  const float* wv_b = (const float*)d_in[5];
  const float* we_w = (const float*)d_in[6];
  float* out = (float*)d_out;
  const int T = out_size / (BB * DD);

  float* att_x = (float*)d_ws;                     // 64*256*256 floats (16 MB)
  float* wvT   = att_x + (size_t)BB * SS * DD;     // 65536 floats
  float* att_r = wvT + DD * DD;                    // 64*DD reserved
  float* score = att_r + 64 * DD;                  // B*T*256 floats (softmax'd in place)

  k_prep   <<<dim3(16 + T), 256, 0, stream>>>(wv_w, wo_w, wo_b, wvT, att_r, T);
  k_attx   <<<dim3(8, BB), 256, 0, stream>>>(x, wvT, wv_b, att_x);
  k_score2 <<<dim3(4, BB), 1024, 0, stream>>>(att_x, att_r, we_w, score, T);
  k_softmax<<<dim3(T, BB), 64, 0, stream>>>(score, T);
  k_out    <<<dim3(BB, 4), 1024, 0, stream>>>(att_x, score, out, T);
}

// Round 6
// 89.016 us; speedup vs baseline: 1.5222x; 1.1385x over previous
//
#include <hip/hip_runtime.h>

#define DD 256
#define BB 64
#define SS 256                       // H*W
#define K2 2.8853900817779268f      // 2*log2(e)
#define LOG2E 1.4426950408889634f
#define MAXT 32

#if __has_builtin(__builtin_amdgcn_exp2f)
#define EXP2(x) __builtin_amdgcn_exp2f(x)
#else
#define EXP2(x) exp2f(x)
#endif

static __device__ __forceinline__ float fast_rcp(float x) {
  return __builtin_amdgcn_rcpf(x);
}

// ---- kernel 1: transpose wv_w into wvT (blocks 0..15) + att_r = pe@wo^T+b (blocks 16..16+T) ----
__global__ __launch_bounds__(256) void k_prep(
    const float* __restrict__ wv_w,
    const float* __restrict__ wo_w, const float* __restrict__ wo_b,
    float* __restrict__ wvT, float* __restrict__ att_r, int T)
{
  const int tid = threadIdx.x;
  if (blockIdx.x < 16) {
    const int bi = blockIdx.x >> 2;   // d-tile
    const int bj = blockIdx.x & 3;    // c-tile
    __shared__ float tile[64 * 65];
#pragma unroll
    for (int p = 0; p < 4; ++p) {
      int row = p * 16 + (tid >> 4);          // local d
      int col = (tid & 15) * 4;               // local c
      float4 v = *reinterpret_cast<const float4*>(wv_w + (size_t)(bi*64 + row)*DD + bj*64 + col);
      tile[row*65 + col + 0] = v.x;
      tile[row*65 + col + 1] = v.y;
      tile[row*65 + col + 2] = v.z;
      tile[row*65 + col + 3] = v.w;
    }
    __syncthreads();
#pragma unroll
    for (int p = 0; p < 4; ++p) {
      int orow = p * 16 + (tid >> 4);   // local c
      int ocol = (tid & 15) * 4;        // local d
      float4 o;
      o.x = tile[(ocol+0)*65 + orow];
      o.y = tile[(ocol+1)*65 + orow];
      o.z = tile[(ocol+2)*65 + orow];
      o.w = tile[(ocol+3)*65 + orow];
      *reinterpret_cast<float4*>(wvT + (size_t)(bj*64 + orow)*DD + bi*64 + ocol) = o;
    }
    return;
  }
  // ---- att_r branch ----
  const int t = blockIdx.x - 16;
  if (t >= T) return;
  __shared__ float pe[DD];
  {
    int i = tid >> 1;
    double r = pow(10000.0, -(double)(2*i) / 256.0);
    double ang = (double)t * r;
    pe[tid] = (float)((tid & 1) ? cos(ang) : sin(ang));
  }
  __syncthreads();
  const float4* wr = reinterpret_cast<const float4*>(wo_w + (size_t)tid * DD);
  const float4* pp = reinterpret_cast<const float4*>(pe);
  float acc = 0.f;
#pragma unroll 8
  for (int k = 0; k < 64; ++k) {
    float4 w4 = wr[k]; float4 p4 = pp[k];
    acc = fmaf(w4.x, p4.x, acc);
    acc = fmaf(w4.y, p4.y, acc);
    acc = fmaf(w4.z, p4.z, acc);
    acc = fmaf(w4.w, p4.w, acc);
  }
  att_r[(size_t)t*DD + tid] = acc + wo_b[tid];
}

// ---- kernel 2: att_x[b][s][d] = sum_c x[b][c][s] * wvT[c][d] + wv_b[d] ----
// grid (8 sT, 2 dT, 64 b) = 1024 blocks (4/CU, 16 waves/CU), block 256.
// Output tile 32s x 128d; thread sg=tid>>5 (4 s), dg=tid&31 (4 d).
// Double-buffered LDS chunks, ONE barrier per K-chunk.
__global__ __launch_bounds__(256) void k_attx(
    const float* __restrict__ x, const float* __restrict__ wvT,
    const float* __restrict__ wv_b, float* __restrict__ att_x)
{
  const int b  = blockIdx.z;
  const int dT = blockIdx.y;           // 0..1 -> d-half
  const int s0 = blockIdx.x * 32;
  const int tid = threadIdx.x;
  const int sg = tid >> 5;             // 0..7
  const int dg = tid & 31;             // 0..31
  const float* xb = x + (size_t)b * DD * SS;   // [c][s]

  __shared__ float wt[2][16 * 128];    // 2 x 8 KB
  __shared__ float xs[2][16 * 32];     // 2 x 2 KB

  float acc[4][4];
#pragma unroll
  for (int j = 0; j < 4; ++j)
#pragma unroll
    for (int r = 0; r < 4; ++r) acc[j][r] = 0.f;

  // staging addresses (lane-consecutive LDS, coalesced global)
  // w: flat = k*256 + tid (k=0,1): row = flat>>5 (0..15), col = (flat&31)*4
  const int wrow0 = tid >> 5;          // k=0 rows 0..7
  const int wcol  = (tid & 31) * 4;
  const float* wsrc0 = wvT + (size_t)wrow0 * DD + dT * 128 + wcol;        // + cc*16*DD
  const float* wsrc1 = wsrc0 + (size_t)8 * DD;                            // k=1 rows 8..15
  // x: tid<128: row = tid>>3 (0..15), col = (tid&7)*4
  const float* xsrc = xb + (size_t)(tid >> 3) * SS + s0 + (tid & 7) * 4;  // + cc*16*SS

  float4 wA0 = *reinterpret_cast<const float4*>(wsrc0);
  float4 wA1 = *reinterpret_cast<const float4*>(wsrc1);
  float4 xA  = make_float4(0.f, 0.f, 0.f, 0.f);
  if (tid < 128) xA = *reinterpret_cast<const float4*>(xsrc);

  int cur = 0;
  for (int cc = 0; cc < 16; ++cc) {
    // write staged regs -> buf[cur] (lane-consecutive float4: conflict-free)
    *reinterpret_cast<float4*>(&wt[cur][tid * 4])        = wA0;
    *reinterpret_cast<float4*>(&wt[cur][1024 + tid * 4]) = wA1;
    if (tid < 128) *reinterpret_cast<float4*>(&xs[cur][tid * 4]) = xA;
    if (cc < 15) {                                  // prefetch next chunk -> regs
      wA0 = *reinterpret_cast<const float4*>(wsrc0 + (size_t)(cc + 1) * 16 * DD);
      wA1 = *reinterpret_cast<const float4*>(wsrc1 + (size_t)(cc + 1) * 16 * DD);
      if (tid < 128) xA = *reinterpret_cast<const float4*>(xsrc + (size_t)(cc + 1) * 16 * SS);
    }
    __syncthreads();                                // buf[cur] visible to all
#pragma unroll
    for (int ci = 0; ci < 16; ++ci) {
      float4 xv = *reinterpret_cast<const float4*>(&xs[cur][ci * 32 + sg * 4]);   // broadcast
      float4 wv = *reinterpret_cast<const float4*>(&wt[cur][ci * 128 + dg * 4]);  // consecutive
      const float xarr[4] = {xv.x, xv.y, xv.z, xv.w};
#pragma unroll
      for (int j = 0; j < 4; ++j) {
        acc[j][0] = fmaf(xarr[j], wv.x, acc[j][0]);
        acc[j][1] = fmaf(xarr[j], wv.y, acc[j][1]);
        acc[j][2] = fmaf(xarr[j], wv.z, acc[j][2]);
        acc[j][3] = fmaf(xarr[j], wv.w, acc[j][3]);
      }
    }
    cur ^= 1;
    // next iteration writes buf[cur^1]: rewritten only after the barrier above
    // has guaranteed every wave finished reading it (2-iteration reuse distance)
  }

  float4 bv = *reinterpret_cast<const float4*>(wv_b + dT * 128 + dg * 4);
#pragma unroll
  for (int j = 0; j < 4; ++j) {
    float4 o;
    o.x = acc[j][0] + bv.x; o.y = acc[j][1] + bv.y;
    o.z = acc[j][2] + bv.z; o.w = acc[j][3] + bv.w;
    float* dst = att_x + ((size_t)(b * SS + s0 + sg * 4 + j)) * DD + dT * 128 + dg * 4;
    *reinterpret_cast<float4*>(dst) = o;
  }
}

// ---- kernel 3: raw scores (no softmax).  grid (4 s-tiles of 64, 64 b), block 1024. ----
// thread: s = tid>>4 (64 s/block), c = tid&15 owns d in [c*16, c*16+16).
// frag = 16 regs -> att_x read ONCE; T-loop (all 26 t) inside, no barriers in loop.
__global__ __launch_bounds__(1024) void k_score2(
    const float* __restrict__ att_x, const float* __restrict__ att_r,
    const float* __restrict__ we_w, float* __restrict__ score, int T)
{
  const int b  = blockIdx.y;
  const int s0 = blockIdx.x * 64;
  const int tid = threadIdx.x;
  const int s  = tid >> 4;       // 0..63
  const int c  = tid & 15;       // 0..15

  __shared__ float attrS[MAXT * 320];   // [t][c*20 + j], c-stride 20: 2-way bank alias (free)
  __shared__ float scS[MAXT * 64];

  // frag[j] = K2 * att_x[b][s0+s][c*16 + j]
  float f0x, f0y, f0z, f0w, f1x, f1y, f1z, f1w;
  float f2x, f2y, f2z, f2w, f3x, f3y, f3z, f3w;
  {
    const float4* ax4 = reinterpret_cast<const float4*>(
        att_x + ((size_t)(b * SS + s0 + s)) * DD + c * 16);
    float4 a = ax4[0], bq = ax4[1], cq = ax4[2], dq = ax4[3];
    f0x = a.x*K2;  f0y = a.y*K2;  f0z = a.z*K2;  f0w = a.w*K2;
    f1x = bq.x*K2; f1y = bq.y*K2; f1z = bq.z*K2; f1w = bq.w*K2;
    f2x = cq.x*K2; f2y = cq.y*K2; f2z = cq.z*K2; f2w = cq.w*K2;
    f3x = dq.x*K2; f3y = dq.y*K2; f3z = dq.z*K2; f3w = dq.w*K2;
  }
  // we (tl-invariant) -> regs
  float4 w0, w1, w2, w3;
  {
    const float4* we4 = reinterpret_cast<const float4*>(we_w + c * 16);
    w0 = we4[0]; w1 = we4[1]; w2 = we4[2]; w3 = we4[3];
  }
  // stage att_r * K2 into LDS (padded layout)
  for (int idx = tid; idx < T * 256; idx += 1024) {
    int t = idx >> 8, d = idx & 255;
    attrS[t * 320 + (d >> 4) * 20 + (d & 15)] = att_r[(size_t)t * DD + d] * K2;
  }
  __syncthreads();

  for (int tl = 0; tl < T; ++tl) {
    const float* aS = &attrS[tl * 320 + c * 20];
    float4 a0 = *reinterpret_cast<const float4*>(aS);
    float4 a1 = *reinterpret_cast<const float4*>(aS + 4);
    float4 a2 = *reinterpret_cast<const float4*>(aS + 8);
    float4 a3 = *reinterpret_cast<const float4*>(aS + 12);
    float part = 0.f;
    part = fmaf(w0.x, fast_rcp(EXP2(f0x + a0.x) + 1.f), part);
    part = fmaf(w0.y, fast_rcp(EXP2(f0y + a0.y) + 1.f), part);
    part = fmaf(w0.z, fast_rcp(EXP2(f0z + a0.z) + 1.f), part);
    part = fmaf(w0.w, fast_rcp(EXP2(f0w + a0.w) + 1.f), part);
    part = fmaf(w1.x, fast_rcp(EXP2(f1x + a1.x) + 1.f), part);
    part = fmaf(w1.y, fast_rcp(EXP2(f1y + a1.y) + 1.f), part);
    part = fmaf(w1.z, fast_rcp(EXP2(f1z + a1.z) + 1.f), part);
    part = fmaf(w1.w, fast_rcp(EXP2(f1w + a1.w) + 1.f), part);
    part = fmaf(w2.x, fast_rcp(EXP2(f2x + a2.x) + 1.f), part);
    part = fmaf(w2.y, fast_rcp(EXP2(f2y + a2.y) + 1.f), part);
    part = fmaf(w2.z, fast_rcp(EXP2(f2z + a2.z) + 1.f), part);
    part = fmaf(w2.w, fast_rcp(EXP2(f2w + a2.w) + 1.f), part);
    part = fmaf(w3.x, fast_rcp(EXP2(f3x + a3.x) + 1.f), part);
    part = fmaf(w3.y, fast_rcp(EXP2(f3y + a3.y) + 1.f), part);
    part = fmaf(w3.z, fast_rcp(EXP2(f3z + a3.z) + 1.f), part);
    part = fmaf(w3.w, fast_rcp(EXP2(f3w + a3.w) + 1.f), part);
    // reduce over c (lane bits 0..3)
    part += __shfl_xor(part, 1);
    part += __shfl_xor(part, 2);
    part += __shfl_xor(part, 4);
    part += __shfl_xor(part, 8);
    if (c == 0) scS[tl * 64 + s] = -2.f * part;   // + softmax-invariant const (dropped)
  }
  __syncthreads();
  // coalesced score write: score[b][t][s0+sl]
  for (int idx = tid; idx < T * 64; idx += 1024) {
    int t = idx >> 6, sl = idx & 63;
    score[((size_t)b * T + t) * SS + s0 + sl] = scS[idx];
  }
}

// ---- kernel 3b: softmax in-place over score rows.  grid (T, 64 b), block 64 (1 wave). ----
__global__ __launch_bounds__(64) void k_softmax(float* __restrict__ score, int T)
{
  const int t = blockIdx.x;
  const int b = blockIdx.y;
  const int lane = threadIdx.x;
  float4* row = reinterpret_cast<float4*>(score + ((size_t)b * T + t) * SS);
  float4 v = row[lane];
  float m = fmaxf(fmaxf(v.x, v.y), fmaxf(v.z, v.w));
  m = fmaxf(m, __shfl_xor(m, 1));
  m = fmaxf(m, __shfl_xor(m, 2));
  m = fmaxf(m, __shfl_xor(m, 4));
  m = fmaxf(m, __shfl_xor(m, 8));
  m = fmaxf(m, __shfl_xor(m, 16));
  m = fmaxf(m, __shfl_xor(m, 32));
  float4 ev;
  ev.x = EXP2((v.x - m) * LOG2E);
  ev.y = EXP2((v.y - m) * LOG2E);
  ev.z = EXP2((v.z - m) * LOG2E);
  ev.w = EXP2((v.w - m) * LOG2E);
  float ss = ev.x + ev.y + ev.z + ev.w;
  ss += __shfl_xor(ss, 1);
  ss += __shfl_xor(ss, 2);
  ss += __shfl_xor(ss, 4);
  ss += __shfl_xor(ss, 8);
  ss += __shfl_xor(ss, 16);
  ss += __shfl_xor(ss, 32);
  float r = fast_rcp(ss);
  ev.x *= r; ev.y *= r; ev.z *= r; ev.w *= r;
  row[lane] = ev;
}

// ---- kernel 4: out[b][t][d] = (1/256) * sum_s alpha[b][t][s] * att_x[b][s][d] ----
// grid (64 b, 4 tg): same-b blocks land on the SAME XCD (stride 64 % 8 == 0).
__global__ __launch_bounds__(1024) void k_out(
    const float* __restrict__ att_x, const float* __restrict__ alpha,
    float* __restrict__ out, int T)
{
  const int b  = blockIdx.x;
  const int tg = blockIdx.y;
  const int tchunk = (T + 3) >> 2;
  const int t0 = tg * tchunk;
  const int nT = (T - t0 < tchunk) ? (T - t0) : tchunk;
  if (nT <= 0) return;
  const int tid = threadIdx.x;
  const int d   = tid & 255;
  const int scg = tid >> 8;   // 0..3

  __shared__ float al[7 * 256];
  __shared__ float red[4 * 7 * 256];

  for (int idx = tid; idx < 7*256; idx += 1024)
    al[idx] = (idx < nT*256) ? alpha[((size_t)b*T + t0)*SS + idx] : 0.f;
  __syncthreads();

  float v[64];
  const float* ax = att_x + ((size_t)(b*SS) + scg*64) * DD + d;
#pragma unroll
  for (int i = 0; i < 64; ++i) v[i] = ax[(size_t)i * DD];

#pragma unroll
  for (int tl = 0; tl < 7; ++tl) {
    float a = 0.f;
#pragma unroll
    for (int i4 = 0; i4 < 16; ++i4) {
      float4 a4 = *reinterpret_cast<const float4*>(&al[tl*256 + scg*64 + i4*4]);  // wave-uniform
      a = fmaf(a4.x, v[i4*4+0], a);
      a = fmaf(a4.y, v[i4*4+1], a);
      a = fmaf(a4.z, v[i4*4+2], a);
      a = fmaf(a4.w, v[i4*4+3], a);
    }
    red[scg*1792 + tl*256 + d] = a;
  }
  __syncthreads();
  for (int idx = tid; idx < nT*256; idx += 1024) {
    float sum = red[idx] + red[1792 + idx] + red[2*1792 + idx] + red[3*1792 + idx];
    out[((size_t)b*T + t0)*SS + idx] = sum * (1.0f/256.0f);
  }
}

extern "C" void kernel_launch(void* const* d_in, const int* in_sizes, int n_in,
                              void* d_out, int out_size, void* d_ws, size_t ws_size,
                              hipStream_t stream) {
  (void)in_sizes; (void)n_in; (void)ws_size;
  const float* x    = (const float*)d_in[0];
  // d_in[1] = seq_len (device int scalar) -- T derived from out_size instead
  const float* wo_w = (const float*)d_in[2];
  const float* wo_b = (const float*)d_in[3];
  const float* wv_w = (const float*)d_in[4];
  const float* wv_b = (const float*)d_in[5];
  const float* we_w = (const float*)d_in[6];
  float* out = (float*)d_out;
  const int T = out_size / (BB * DD);

  float* att_x = (float*)d_ws;                     // 64*256*256 floats (16 MB)
  float* wvT   = att_x + (size_t)BB * SS * DD;     // 65536 floats
  float* att_r = wvT + DD * DD;                    // 64*DD reserved
  float* score = att_r + 64 * DD;                  // B*T*256 floats (softmax'd in place)

  k_prep   <<<dim3(16 + T), 256, 0, stream>>>(wv_w, wo_w, wo_b, wvT, att_r, T);
  k_attx   <<<dim3(8, 2, BB), 256, 0, stream>>>(x, wvT, wv_b, att_x);
  k_score2 <<<dim3(4, BB), 1024, 0, stream>>>(att_x, att_r, we_w, score, T);
  k_softmax<<<dim3(T, BB), 64, 0, stream>>>(score, T);
  k_out    <<<dim3(BB, 4), 1024, 0, stream>>>(att_x, score, out, T);
}